// Round 2
// baseline (48.037 us; speedup 1.0000x reference)
//
#include <hip/hip_runtime.h>
#include <math.h>

// SpectralContrastPrior: per (b, band, t) column, mean of top-3 and bottom-3
// over the band's frequency rows (170 for bands 0..4, 175 for band 5).
// Input:  power_spec (32, 1025, 2000) f32
// Output: peaks (32, 6, 2000) f32 followed by valleys (32, 6, 2000) f32, flat.
//
// k = int(170*0.02) = int(175*0.02) = 3 for all bands -> running top-3/bot-3
// via a 5-op min/max insert network; no sort needed. Memory-bound streaming:
// 262 MB read once, 3 MB write.

constexpr int B_   = 32;
constexpr int NF   = 1025;
constexpr int T_   = 2000;
constexpr int NB   = 6;
constexpr int BAND = NF / NB;   // 170
constexpr int VEC  = 4;         // float4 per thread along t (16 B/lane loads)
constexpr int TG   = T_ / VEC;  // 500

// Maintain sorted top-3 (t0 >= t1 >= t2): 5 min/max ops.
__device__ __forceinline__ void ins_top(float& t0, float& t1, float& t2, float x) {
    float lo0 = fminf(t0, x);
    t0 = fmaxf(t0, x);
    float lo1 = fminf(t1, lo0);
    t1 = fmaxf(t1, lo0);
    t2 = fmaxf(t2, lo1);
}
// Maintain sorted bottom-3 (b0 <= b1 <= b2): 5 min/max ops.
__device__ __forceinline__ void ins_bot(float& b0, float& b1, float& b2, float x) {
    float hi0 = fmaxf(b0, x);
    b0 = fminf(b0, x);
    float hi1 = fmaxf(b1, hi0);
    b1 = fminf(b1, hi0);
    b2 = fminf(b2, hi1);
}

struct Acc3 {
    float x0, x1, x2;   // top-3
    float n0, n1, n2;   // bottom-3
    __device__ __forceinline__ void init() {
        x0 = x1 = x2 = -INFINITY;
        n0 = n1 = n2 =  INFINITY;
    }
    __device__ __forceinline__ void push(float v) {
        ins_top(x0, x1, x2, v);
        ins_bot(n0, n1, n2, v);
    }
};

__global__ __launch_bounds__(128) void scp_kernel(const float* __restrict__ in,
                                                  float* __restrict__ out) {
    int idx = blockIdx.x * blockDim.x + threadIdx.x;
    if (idx >= B_ * NB * TG) return;

    int tg   = idx % TG;          // consecutive lanes -> consecutive t: coalesced
    int rest = idx / TG;
    int band = rest % NB;
    int b    = rest / NB;

    int row0  = band * BAND;
    int nrows = (band == NB - 1) ? (NF - row0) : BAND;   // 175 or 170

    const float* p = in + (size_t)b * NF * T_ + (size_t)row0 * T_ + (size_t)tg * VEC;

    Acc3 a0, a1, a2, a3;
    a0.init(); a1.init(); a2.init(); a3.init();

    #pragma unroll 5   // 170 % 5 == 0 and 175 % 5 == 0
    for (int r = 0; r < nrows; ++r) {
        float4 v = *reinterpret_cast<const float4*>(p + (size_t)r * T_);
        a0.push(v.x);
        a1.push(v.y);
        a2.push(v.z);
        a3.push(v.w);
    }

    const float inv3 = 1.0f / 3.0f;
    size_t o    = (size_t)b * NB * T_ + (size_t)band * T_ + (size_t)tg * VEC;
    size_t voff = (size_t)B_ * NB * T_;

    float4 pk = make_float4((a0.x0 + a0.x1 + a0.x2) * inv3,
                            (a1.x0 + a1.x1 + a1.x2) * inv3,
                            (a2.x0 + a2.x1 + a2.x2) * inv3,
                            (a3.x0 + a3.x1 + a3.x2) * inv3);
    float4 vl = make_float4((a0.n0 + a0.n1 + a0.n2) * inv3,
                            (a1.n0 + a1.n1 + a1.n2) * inv3,
                            (a2.n0 + a2.n1 + a2.n2) * inv3,
                            (a3.n0 + a3.n1 + a3.n2) * inv3);
    *reinterpret_cast<float4*>(out + o)        = pk;   // peaks
    *reinterpret_cast<float4*>(out + voff + o) = vl;   // valleys
}

extern "C" void kernel_launch(void* const* d_in, const int* in_sizes, int n_in,
                              void* d_out, int out_size, void* d_ws, size_t ws_size,
                              hipStream_t stream) {
    const float* in = (const float*)d_in[0];
    float* out = (float*)d_out;

    int total = B_ * NB * TG;                 // 96000 threads
    int block = 128;                          // 2 waves/block
    int grid  = (total + block - 1) / block;  // 750 blocks (same dist. as R1)
    scp_kernel<<<grid, block, 0, stream>>>(in, out);
}